// Round 5
// baseline (189.819 us; speedup 1.0000x reference)
//
#include <hip/hip_runtime.h>
#include <hip/hip_bf16.h>

typedef __attribute__((ext_vector_type(8))) short bf16x8;
typedef __attribute__((ext_vector_type(4))) float f32x4;

#define D        256
#define NH       512
#define NT       32               // n-tiles (16 cols each)
#define KT       8                // k-steps (32 each)
#define MT       4                // M-tiles (16 rows) per wave -> 64 rows
#define WAVES    2                // 128-thread blocks
#define ROWS_PER_WAVE  64
#define ROWS_PER_BLOCK 128
#define ROWS_TOTAL (32*8192)      // 262144
#define NPHASE   (NT/2)           // 16 phases, 2 nt per phase

typedef __attribute__((address_space(1))) const void GV;
typedef __attribute__((address_space(3))) void LV;

__device__ __forceinline__ short f2bf(float f) {
    union { float f; unsigned u; } v; v.f = f;
    unsigned r = v.u + 0x7FFFu + ((v.u >> 16) & 1u);
    return (short)(r >> 16);
}

__device__ __forceinline__ float rcp_fast(float x) {
    return __builtin_amdgcn_rcpf(x);
}

// Pack We (fp32 [256][512]) into bf16 MFMA B-fragments:
// frag[(nt*8+kt)*64 + lane][j] = We[kt*32 + (lane>>4)*8 + j][nt*16 + (lane&15)]
// Also: bias2[n] = 2*be[n]; Ssum = sum(Wr).
__global__ void prepack_B(const float* __restrict__ We, const float* __restrict__ be,
                          const float* __restrict__ Wr,
                          short* __restrict__ Bh, float* __restrict__ bias2,
                          float* __restrict__ Ssum) {
    int i = blockIdx.x * 256 + threadIdx.x;      // 131072 elements
    int k = i >> 9;
    int n = i & 511;
    int nt = n >> 4, c = n & 15;
    int kt = k >> 5, g = (k >> 3) & 3, j = k & 7;
    int idx = (((nt * 8 + kt) * 64) + (g * 16 + c)) * 8 + j;
    Bh[idx] = f2bf(We[i]);
    if (i < 512) bias2[i] = 2.0f * be[i];
    if (i == 0) {
        float s = 0.0f;
        for (int t = 0; t < 512; ++t) s += Wr[t];
        Ssum[0] = s;
    }
}

__global__ __launch_bounds__(128, 2) void softpool_main(
    const float* __restrict__ x, const short* __restrict__ Bh,
    const float* __restrict__ bias2, const float* __restrict__ Wr,
    const float* __restrict__ br, const float* __restrict__ Ssum,
    float* __restrict__ out)
{
    const int lane = threadIdx.x & 63;
    const int wave = threadIdx.x >> 6;           // 0..1
    const int c = lane & 15;     // A row-in-tile / C col / B col
    const int g = lane >> 4;     // k-group
    const long row0 = (long)blockIdx.x * ROWS_PER_BLOCK + (long)wave * ROWS_PER_WAVE;

    __shared__ short Bl[2][2][4096];   // [buf][nt-in-phase][frag] = 32 KB

    // Wave stages kt = 4*wave .. 4*wave+3 (1KB each) for both nt of the phase.
    const int kt0 = wave * 4;
    const short* gB = Bh + (long)kt0 * 512 + lane * 8;

    #define STAGE(buf, ph) {                                                   \
        _Pragma("unroll")                                                      \
        for (int nto = 0; nto < 2; ++nto) {                                    \
            const short* _g = gB + ((long)((ph) * 2 + nto) * 4096);            \
            _Pragma("unroll")                                                  \
            for (int kk = 0; kk < 4; ++kk)                                     \
                __builtin_amdgcn_global_load_lds((GV*)(_g + kk * 512),         \
                    (LV*)&Bl[buf][nto][(kt0 + kk) * 512], 16, 0, 0);           \
        }                                                                      \
    }

    // Prologue: stage phase 0 into buf 0 (issued before the A HBM loads)
    STAGE(0, 0)

    // ---- Load A fragments (4 Mtiles x 8 k-steps), fp32 -> bf16, keep in regs
    bf16x8 a[MT][KT];
    #pragma unroll
    for (int m = 0; m < MT; ++m) {
        const float* xr = x + (row0 + m * 16 + c) * D + g * 8;
        #pragma unroll
        for (int kt = 0; kt < KT; ++kt) {
            float4 v0 = *(const float4*)(xr + kt * 32);
            float4 v1 = *(const float4*)(xr + kt * 32 + 4);
            bf16x8 t;
            t[0] = f2bf(v0.x); t[1] = f2bf(v0.y); t[2] = f2bf(v0.z); t[3] = f2bf(v0.w);
            t[4] = f2bf(v1.x); t[5] = f2bf(v1.y); t[6] = f2bf(v1.z); t[7] = f2bf(v1.w);
            a[m][kt] = t;
        }
    }

    // lps[m][r] accumulates sum_n Wr[n] * rcp(exp(2*y)+1); logit = S - 2*lps + br
    float lps[MT][4];
    #pragma unroll
    for (int m = 0; m < MT; ++m)
        #pragma unroll
        for (int r = 0; r < 4; ++r) lps[m][r] = 0.0f;

    __syncthreads();   // phase-0 staging complete

    #define COMPUTE(buf, nto, ntv) {                                           \
        f32x4 acc[MT];                                                         \
        _Pragma("unroll")                                                      \
        for (int m = 0; m < MT; ++m)                                           \
            _Pragma("unroll")                                                  \
            for (int r = 0; r < 4; ++r) acc[m][r] = 0.0f;                      \
        _Pragma("unroll")                                                      \
        for (int kt = 0; kt < KT; ++kt) {                                      \
            bf16x8 b = *(const bf16x8*)&Bl[buf][nto][kt * 512 + lane * 8];     \
            _Pragma("unroll")                                                  \
            for (int m = 0; m < MT; ++m)                                       \
                acc[m] = __builtin_amdgcn_mfma_f32_16x16x32_bf16(              \
                             a[m][kt], b, acc[m], 0, 0, 0);                    \
        }                                                                      \
        int n = (ntv) * 16 + c;                                                \
        float b2 = bias2[n];                                                   \
        float vr = Wr[n];                                                      \
        _Pragma("unroll")                                                      \
        for (int m = 0; m < MT; ++m)                                           \
            _Pragma("unroll")                                                  \
            for (int r = 0; r < 4; ++r) {                                      \
                float z = __builtin_fmaf(acc[m][r], 2.0f, b2);                 \
                float e = __expf(z);                                           \
                float rr = rcp_fast(e + 1.0f);                                 \
                lps[m][r] = __builtin_fmaf(vr, rr, lps[m][r]);                 \
            }                                                                  \
    }

    // ---- Main loop: 16 phases, 2 nt each, LDS double-buffered, 1 barrier/phase
    int buf = 0;
    for (int p = 0; p < NPHASE; ++p) {
        if (p + 1 < NPHASE) STAGE(buf ^ 1, p + 1)
        COMPUTE(buf, 0, 2 * p)
        COMPUTE(buf, 1, 2 * p + 1)
        __syncthreads();
        buf ^= 1;
    }

    // ---- Reduce partial sums over the 16 cols; softmax(sigmoid); weighted out
    const float brv = br[0];
    const float S = Ssum[0];
    #pragma unroll
    for (int m = 0; m < MT; ++m) {
        float l0 = lps[m][0], l1 = lps[m][1], l2 = lps[m][2], l3 = lps[m][3];
        #pragma unroll
        for (int off = 1; off < 16; off <<= 1) {
            l0 += __shfl_xor(l0, off, 64);
            l1 += __shfl_xor(l1, off, 64);
            l2 += __shfl_xor(l2, off, 64);
            l3 += __shfl_xor(l3, off, 64);
        }
        // logit = S - 2*lps + br ; s = sigmoid(logit)
        float g0 = S - 2.0f * l0 + brv;
        float g1 = S - 2.0f * l1 + brv;
        float g2 = S - 2.0f * l2 + brv;
        float g3 = S - 2.0f * l3 + brv;
        float s0 = rcp_fast(1.0f + __expf(-g0));
        float s1 = rcp_fast(1.0f + __expf(-g1));
        float s2 = rcp_fast(1.0f + __expf(-g2));
        float s3 = rcp_fast(1.0f + __expf(-g3));
        float e0 = __expf(s0), e1 = __expf(s1), e2 = __expf(s2), e3 = __expf(s3);
        float inv = rcp_fast(e0 + e1 + e2 + e3);
        float w0 = e0 * inv, w1 = e1 * inv, w2 = e2 * inv, w3 = e3 * inv;

        // window = rows [wrow, wrow+3]; lane-group g owns window g of this Mtile
        const long wrow = row0 + m * 16 + g * 4;
        const long W = wrow >> 2;
        const float* xw = x + wrow * D + c * 4;
        float* op = out + W * D + c * 4;
        #pragma unroll
        for (int q = 0; q < 4; ++q) {
            float4 r0 = *(const float4*)(xw + 0 * D + q * 64);
            float4 r1 = *(const float4*)(xw + 1 * D + q * 64);
            float4 r2 = *(const float4*)(xw + 2 * D + q * 64);
            float4 r3 = *(const float4*)(xw + 3 * D + q * 64);
            float4 oo;
            oo.x = w0 * r0.x + w1 * r1.x + w2 * r2.x + w3 * r3.x;
            oo.y = w0 * r0.y + w1 * r1.y + w2 * r2.y + w3 * r3.y;
            oo.z = w0 * r0.z + w1 * r1.z + w2 * r2.z + w3 * r3.z;
            oo.w = w0 * r0.w + w1 * r1.w + w2 * r2.w + w3 * r3.w;
            *(float4*)(op + q * 64) = oo;
        }
    }
}

extern "C" void kernel_launch(void* const* d_in, const int* in_sizes, int n_in,
                              void* d_out, int out_size, void* d_ws, size_t ws_size,
                              hipStream_t stream) {
    const float* x  = (const float*)d_in[0];
    const float* We = (const float*)d_in[1];
    const float* be = (const float*)d_in[2];
    const float* Wr = (const float*)d_in[3];
    const float* br = (const float*)d_in[4];
    float* out = (float*)d_out;

    char* ws = (char*)d_ws;
    short* Bh    = (short*)ws;                    // 262144 B
    float* bias2 = (float*)(ws + 262144);         // 2048 B
    float* Ssum  = (float*)(ws + 262144 + 2048);  // 4 B

    prepack_B<<<NH * D / 256, 256, 0, stream>>>(We, be, Wr, Bh, bias2, Ssum);

    const int blocks = ROWS_TOTAL / ROWS_PER_BLOCK;   // 2048
    softpool_main<<<blocks, 128, 0, stream>>>(x, Bh, bias2, Wr, br, Ssum, out);
}